// Round 1
// baseline (179.913 us; speedup 1.0000x reference)
//
#include <hip/hip_runtime.h>

#define BB 64
#define SS 2048
#define HH 512
#define AA 512
#define MROWS (BB*SS)  // 131072

typedef __attribute__((ext_vector_type(8))) short short8;
typedef __attribute__((ext_vector_type(4))) float f32x4;

__device__ inline unsigned short f2bf(float f){
  unsigned int u = __float_as_uint(f);
  u += 0x7FFFu + ((u >> 16) & 1u);   // RNE
  return (unsigned short)(u >> 16);
}

// batch_lens may be int64 (reference uses jnp.int64) or int32.
// For int64 little-endian, the high word of every element is 0 (lens in [1,2048]);
// for int32, element 1 is a len >= 1. So p32[1]==0  <=>  int64 layout.
__device__ inline int read_len(const void* lens, int i){
  const int* p = (const int*)lens;
  if (p[1] == 0) return (int)((const long long*)lens)[i];
  return p[i];
}

__device__ inline float fast_tanh(float x){
  x = fminf(fmaxf(x, -15.f), 15.f);
  float e = __expf(2.f * x);
  return (e - 1.f) / (e + 1.f);
}

// Pass 1: scores partials. Tile 128x128, K=512, bf16 MFMA.
__global__ __launch_bounds__(256) void scores_kernel(
    const float* __restrict__ X, const void* __restrict__ lens,
    const float* __restrict__ ctx, const float* __restrict__ W,
    const float* __restrict__ pb, float* __restrict__ sp)
{
  // XCD-chunk swizzle: 4096 blocks, 512 contiguous wgs per XCD; n-tile fastest.
  int bid = blockIdx.x;
  int wg = (bid & 7) * 512 + (bid >> 3);
  int ntile = wg & 3;        // 0..3
  int mtile = wg >> 2;       // 0..1023
  int s_start = (mtile * 128) & (SS - 1);
  int b = (mtile * 128) >> 11;
  if (s_start >= read_len(lens, b)) return;  // whole tile masked

  __shared__ unsigned short As[128 * 72];  // +8 pad: 144B row stride, 16B aligned
  __shared__ unsigned short Bs[128 * 72];

  int tid = threadIdx.x;
  int lane = tid & 63;
  int w = tid >> 6;
  int wm = w >> 1, wn = w & 1;
  int l15 = lane & 15, g = lane >> 4;

  f32x4 acc[4][4];
  #pragma unroll
  for (int i = 0; i < 4; i++)
    #pragma unroll
    for (int j = 0; j < 4; j++) acc[i][j] = (f32x4)0.f;

  int srow = tid >> 4;          // 0..15
  int scol = (tid & 15) * 4;    // 0..60

  const float* Xbase = X + (size_t)(mtile * 128) * HH;
  const float* Wbase = W + (size_t)(ntile * 128) * HH;

  for (int kt = 0; kt < HH; kt += 64) {
    #pragma unroll
    for (int i = 0; i < 8; i++) {
      int row = srow + i * 16;
      float4 va = *(const float4*)(Xbase + (size_t)row * HH + kt + scol);
      unsigned int p0 = (unsigned int)f2bf(va.x) | ((unsigned int)f2bf(va.y) << 16);
      unsigned int p1 = (unsigned int)f2bf(va.z) | ((unsigned int)f2bf(va.w) << 16);
      *(uint2*)&As[row * 72 + scol] = make_uint2(p0, p1);
      float4 vb = *(const float4*)(Wbase + (size_t)row * HH + kt + scol);
      unsigned int q0 = (unsigned int)f2bf(vb.x) | ((unsigned int)f2bf(vb.y) << 16);
      unsigned int q1 = (unsigned int)f2bf(vb.z) | ((unsigned int)f2bf(vb.w) << 16);
      *(uint2*)&Bs[row * 72 + scol] = make_uint2(q0, q1);
    }
    __syncthreads();
    #pragma unroll
    for (int kk = 0; kk < 64; kk += 32) {
      short8 af[4], bf[4];
      int ko = kk + g * 8;
      #pragma unroll
      for (int im = 0; im < 4; im++)
        af[im] = *(const short8*)&As[(wm * 64 + im * 16 + l15) * 72 + ko];
      #pragma unroll
      for (int in = 0; in < 4; in++)
        bf[in] = *(const short8*)&Bs[(wn * 64 + in * 16 + l15) * 72 + ko];
      #pragma unroll
      for (int im = 0; im < 4; im++)
        #pragma unroll
        for (int in = 0; in < 4; in++)
          acc[im][in] = __builtin_amdgcn_mfma_f32_16x16x32_bf16(
              af[im], bf[in], acc[im][in], 0, 0, 0);
    }
    __syncthreads();
  }

  // Epilogue: tanh(P + b)*ctx, reduce over this tile's 128 cols -> score partial.
  #pragma unroll
  for (int im = 0; im < 4; im++) {
    #pragma unroll
    for (int r = 0; r < 4; r++) {
      float rowsum = 0.f;
      #pragma unroll
      for (int in = 0; in < 4; in++) {
        int a_g = ntile * 128 + wn * 64 + in * 16 + l15;
        float v = acc[im][in][r] + pb[a_g];
        rowsum += fast_tanh(v) * ctx[a_g];
      }
      #pragma unroll
      for (int m = 1; m < 16; m <<= 1)
        rowsum += __shfl_xor(rowsum, m, 64);
      if (l15 == 0) {
        int rowg = mtile * 128 + wm * 64 + im * 16 + g * 4 + r;
        sp[(size_t)(ntile * 2 + wn) * MROWS + rowg] = rowsum;
      }
    }
  }
}

// Pass 2: masked softmax per batch row. 64 blocks x 256 threads, 8 s/thread.
__global__ __launch_bounds__(256) void softmax_kernel(
    const float* __restrict__ sp, const void* __restrict__ lens,
    float* __restrict__ wts)
{
  int b = blockIdx.x;
  int tid = threadIdx.x;
  int len = read_len(lens, b);
  float sc[8];
  #pragma unroll
  for (int i = 0; i < 8; i++) {
    int s = tid + i * 256;
    size_t row = (size_t)b * SS + s;
    float v = 0.f;
    #pragma unroll
    for (int p = 0; p < 8; p++) v += sp[(size_t)p * MROWS + row];
    sc[i] = v;
  }
  float m = -1e30f;
  #pragma unroll
  for (int i = 0; i < 8; i++)
    if (tid + i * 256 < len) m = fmaxf(m, sc[i]);
  #pragma unroll
  for (int off = 1; off < 64; off <<= 1) m = fmaxf(m, __shfl_xor(m, off, 64));
  __shared__ float redm[4];
  __shared__ float reds[4];
  int w = tid >> 6, lane = tid & 63;
  if (lane == 0) redm[w] = m;
  __syncthreads();
  m = fmaxf(fmaxf(redm[0], redm[1]), fmaxf(redm[2], redm[3]));
  float e[8]; float sum = 0.f;
  #pragma unroll
  for (int i = 0; i < 8; i++) {
    int s = tid + i * 256;
    e[i] = (s < len) ? __expf(sc[i] - m) : 0.f;
    sum += e[i];
  }
  #pragma unroll
  for (int off = 1; off < 64; off <<= 1) sum += __shfl_xor(sum, off, 64);
  if (lane == 0) reds[w] = sum;
  __syncthreads();
  sum = reds[0] + reds[1] + reds[2] + reds[3];
  float inv = 1.f / sum;
  #pragma unroll
  for (int i = 0; i < 8; i++) {
    int s = tid + i * 256;
    wts[(size_t)b * SS + s] = e[i] * inv;   // exact 0 for masked s
  }
}

// Pass 3: out[b,h] partials = sum_s w[b,s] * X[b,s,h], 128 s per block.
__global__ __launch_bounds__(256) void wsum_kernel(
    const float* __restrict__ X, const float* __restrict__ wts,
    float* __restrict__ op)
{
  int sc = blockIdx.x;   // 0..15
  int b  = blockIdx.y;   // 0..63
  int tid = threadIdx.x;
  float a0 = 0.f, a1 = 0.f;
  int s0 = sc * 128;
  for (int i = 0; i < 128; i++) {
    int s = s0 + i;
    float wv = wts[(size_t)b * SS + s];
    if (wv != 0.f) {   // uniform branch; skips masked tail
      const float* xr = X + ((size_t)b * SS + s) * HH;
      a0 += wv * xr[tid];
      a1 += wv * xr[tid + 256];
    }
  }
  float* o = op + ((size_t)sc * BB + b) * HH;
  o[tid] = a0;
  o[tid + 256] = a1;
}

__global__ __launch_bounds__(512) void reduce_kernel(
    const float* __restrict__ op, float* __restrict__ out)
{
  int b = blockIdx.x;
  int h = threadIdx.x;
  float v = 0.f;
  #pragma unroll
  for (int sc = 0; sc < 16; sc++) v += op[((size_t)sc * BB + b) * HH + h];
  out[(size_t)b * HH + h] = v;
}

extern "C" void kernel_launch(void* const* d_in, const int* in_sizes, int n_in,
                              void* d_out, int out_size, void* d_ws, size_t ws_size,
                              hipStream_t stream) {
  const float* X   = (const float*)d_in[0];
  const void*  lens = d_in[1];
  const float* ctx = (const float*)d_in[2];
  const float* W   = (const float*)d_in[3];
  const float* pb  = (const float*)d_in[4];
  float* out = (float*)d_out;

  char* ws = (char*)d_ws;
  float* sp  = (float*)ws;                                   // 8*131072*4 = 4 MB
  float* wts = (float*)(ws + 8ull * MROWS * 4);              // 512 KB
  float* op  = (float*)(ws + 8ull * MROWS * 4 + (size_t)BB * SS * 4); // 2 MB

  scores_kernel<<<4096, 256, 0, stream>>>(X, lens, ctx, W, pb, sp);
  softmax_kernel<<<BB, 256, 0, stream>>>(sp, lens, wts);
  wsum_kernel<<<dim3(16, BB), 256, 0, stream>>>(X, wts, op);
  reduce_kernel<<<BB, 512, 0, stream>>>(op, out);
}

// Round 2
// 179.443 us; speedup vs baseline: 1.0026x; 1.0026x over previous
//
#include <hip/hip_runtime.h>

#define BB 64
#define SS 2048
#define HH 512
#define MROWS (BB*SS)  // 131072

typedef __attribute__((ext_vector_type(8))) short short8;
typedef __attribute__((ext_vector_type(4))) float f32x4;

__device__ inline unsigned short f2bf(float f){
  unsigned int u = __float_as_uint(f);
  u += 0x7FFFu + ((u >> 16) & 1u);   // RNE
  return (unsigned short)(u >> 16);
}

// batch_lens may be int64 (reference) or int32. For int64 LE the high word of
// element 0 is 0 (lens in [1,2048]); for int32, p[1] is a len >= 1.
__device__ inline int read_len(const void* lens, int i){
  const int* p = (const int*)lens;
  if (p[1] == 0) return (int)((const long long*)lens)[i];
  return p[i];
}

__device__ inline float fast_tanh(float x){
  x = fminf(fmaxf(x, -15.f), 15.f);
  float e = __expf(2.f * x);
  return (e - 1.f) / (e + 1.f);
}

__device__ inline void gload16(const void* gptr, void* lptr){
  __builtin_amdgcn_global_load_lds(
      (const __attribute__((address_space(1))) void*)gptr,
      (__attribute__((address_space(3))) void*)lptr, 16, 0, 0);
}

// ---------- pre-convert passes ----------
__global__ __launch_bounds__(256) void convw_kernel(
    const float* __restrict__ W, unsigned short* __restrict__ Wb)
{
  size_t idx = (size_t)blockIdx.x * 1024 + threadIdx.x * 4;
  float4 v = *(const float4*)(W + idx);
  unsigned int p0 = (unsigned int)f2bf(v.x) | ((unsigned int)f2bf(v.y) << 16);
  unsigned int p1 = (unsigned int)f2bf(v.z) | ((unsigned int)f2bf(v.w) << 16);
  *(uint2*)(Wb + idx) = make_uint2(p0, p1);
}

__global__ __launch_bounds__(256) void convx_kernel(
    const float* __restrict__ X, const void* __restrict__ lens,
    unsigned short* __restrict__ Xb)
{
  int r0 = blockIdx.x * 64;            // 64 rows per block
  int b = r0 >> 11;
  int s0 = r0 & (SS - 1);
  if (s0 >= read_len(lens, b)) return; // fully masked -> never read by GEMM
  size_t base = (size_t)r0 * HH;
  int t = threadIdx.x;
  #pragma unroll
  for (int j = 0; j < 32; j++) {
    size_t idx = base + (size_t)j * 1024 + t * 4;
    float4 v = *(const float4*)(X + idx);
    unsigned int p0 = (unsigned int)f2bf(v.x) | ((unsigned int)f2bf(v.y) << 16);
    unsigned int p1 = (unsigned int)f2bf(v.z) | ((unsigned int)f2bf(v.w) << 16);
    *(uint2*)(Xb + idx) = make_uint2(p0, p1);
  }
}

// ---------- pass 1: scores via bf16 MFMA, gload_lds staging, swizzled LDS ----------
__global__ __launch_bounds__(256) void scores_mfma(
    const unsigned short* __restrict__ Xb, const unsigned short* __restrict__ Wb,
    const void* __restrict__ lens, const float* __restrict__ ctx,
    const float* __restrict__ pb, float* __restrict__ sp)
{
  int bid = blockIdx.x;
  int wg = (bid & 7) * 512 + (bid >> 3);   // XCD-chunk swizzle (4096 % 8 == 0)
  int ntile = wg & 3;
  int mtile = wg >> 2;
  int s_start = (mtile * 128) & (SS - 1);
  int b = (mtile * 128) >> 11;
  if (s_start >= read_len(lens, b)) return;

  __shared__ __align__(16) unsigned short As[128 * 64];
  __shared__ __align__(16) unsigned short Bs[128 * 64];

  int tid = threadIdx.x;
  int lane = tid & 63;
  int w = tid >> 6;
  int wm = w >> 1, wn = w & 1;
  int l15 = lane & 15, g = lane >> 4;

  f32x4 acc[4][4];
  #pragma unroll
  for (int i = 0; i < 4; i++)
    #pragma unroll
    for (int j = 0; j < 4; j++) acc[i][j] = (f32x4)0.f;

  // staging: wave w, instr i covers LDS rows rb = i*32 + w*8 .. +8.
  // lane l -> LDS slot (row rb + (l>>3), physgroup l&7). Inverse-swizzled
  // global source: logical group (l&7) ^ (l>>3) of that row.
  int lrow = lane >> 3;
  int lgrp = (lane & 7) ^ lrow;
  const unsigned short* Arow = Xb + ((size_t)(mtile * 128) + w * 8 + lrow) * HH + lgrp * 8;
  const unsigned short* Brow = Wb + ((size_t)(ntile * 128) + w * 8 + lrow) * HH + lgrp * 8;

  for (int kt = 0; kt < HH; kt += 64) {
    #pragma unroll
    for (int i = 0; i < 4; i++) {
      gload16(Arow + (size_t)(i * 32) * HH + kt, &As[(i * 32 + w * 8) * 64]);
      gload16(Brow + (size_t)(i * 32) * HH + kt, &Bs[(i * 32 + w * 8) * 64]);
    }
    __syncthreads();
    #pragma unroll
    for (int kk = 0; kk < 64; kk += 32) {
      short8 af[4], bfr[4];
      int lgbase = g + (kk >> 3);          // logical 16B-group: 0..3 or 4..7
      #pragma unroll
      for (int im = 0; im < 4; im++) {
        int r = wm * 64 + im * 16 + l15;
        int pg = lgbase ^ (r & 7);
        af[im] = *(const short8*)&As[r * 64 + pg * 8];
      }
      #pragma unroll
      for (int in = 0; in < 4; in++) {
        int r = wn * 64 + in * 16 + l15;
        int pg = lgbase ^ (r & 7);
        bfr[in] = *(const short8*)&Bs[r * 64 + pg * 8];
      }
      #pragma unroll
      for (int im = 0; im < 4; im++)
        #pragma unroll
        for (int in = 0; in < 4; in++)
          acc[im][in] = __builtin_amdgcn_mfma_f32_16x16x32_bf16(
              af[im], bfr[in], acc[im][in], 0, 0, 0);
    }
    __syncthreads();
  }

  // Epilogue: tanh(P + pb)*ctx, reduce over the tile's 128 A-cols.
  #pragma unroll
  for (int im = 0; im < 4; im++) {
    #pragma unroll
    for (int r = 0; r < 4; r++) {
      float rowsum = 0.f;
      #pragma unroll
      for (int in = 0; in < 4; in++) {
        int a_g = ntile * 128 + wn * 64 + in * 16 + l15;
        float v = acc[im][in][r] + pb[a_g];
        rowsum += fast_tanh(v) * ctx[a_g];
      }
      #pragma unroll
      for (int m = 1; m < 16; m <<= 1)
        rowsum += __shfl_xor(rowsum, m, 64);
      if (l15 == 0) {
        int rowg = mtile * 128 + wm * 64 + im * 16 + g * 4 + r;
        sp[(size_t)(ntile * 2 + wn) * MROWS + rowg] = rowsum;
      }
    }
  }
}

// ---------- fallback pass 1 (round-1 path, used only if ws too small) ----------
__global__ __launch_bounds__(256) void scores_fb(
    const float* __restrict__ X, const void* __restrict__ lens,
    const float* __restrict__ ctx, const float* __restrict__ W,
    const float* __restrict__ pb, float* __restrict__ sp)
{
  int bid = blockIdx.x;
  int wg = (bid & 7) * 512 + (bid >> 3);
  int ntile = wg & 3;
  int mtile = wg >> 2;
  int s_start = (mtile * 128) & (SS - 1);
  int b = (mtile * 128) >> 11;
  if (s_start >= read_len(lens, b)) return;

  __shared__ unsigned short As[128 * 72];
  __shared__ unsigned short Bs[128 * 72];

  int tid = threadIdx.x;
  int lane = tid & 63;
  int w = tid >> 6;
  int wm = w >> 1, wn = w & 1;
  int l15 = lane & 15, g = lane >> 4;

  f32x4 acc[4][4];
  #pragma unroll
  for (int i = 0; i < 4; i++)
    #pragma unroll
    for (int j = 0; j < 4; j++) acc[i][j] = (f32x4)0.f;

  int srow = tid >> 4;
  int scol = (tid & 15) * 4;
  const float* Xbase = X + (size_t)(mtile * 128) * HH;
  const float* Wbase = W + (size_t)(ntile * 128) * HH;

  for (int kt = 0; kt < HH; kt += 64) {
    #pragma unroll
    for (int i = 0; i < 8; i++) {
      int row = srow + i * 16;
      float4 va = *(const float4*)(Xbase + (size_t)row * HH + kt + scol);
      unsigned int p0 = (unsigned int)f2bf(va.x) | ((unsigned int)f2bf(va.y) << 16);
      unsigned int p1 = (unsigned int)f2bf(va.z) | ((unsigned int)f2bf(va.w) << 16);
      *(uint2*)&As[row * 72 + scol] = make_uint2(p0, p1);
      float4 vb = *(const float4*)(Wbase + (size_t)row * HH + kt + scol);
      unsigned int q0 = (unsigned int)f2bf(vb.x) | ((unsigned int)f2bf(vb.y) << 16);
      unsigned int q1 = (unsigned int)f2bf(vb.z) | ((unsigned int)f2bf(vb.w) << 16);
      *(uint2*)&Bs[row * 72 + scol] = make_uint2(q0, q1);
    }
    __syncthreads();
    #pragma unroll
    for (int kk = 0; kk < 64; kk += 32) {
      short8 af[4], bfr[4];
      int ko = kk + g * 8;
      #pragma unroll
      for (int im = 0; im < 4; im++)
        af[im] = *(const short8*)&As[(wm * 64 + im * 16 + l15) * 72 + ko];
      #pragma unroll
      for (int in = 0; in < 4; in++)
        bfr[in] = *(const short8*)&Bs[(wn * 64 + in * 16 + l15) * 72 + ko];
      #pragma unroll
      for (int im = 0; im < 4; im++)
        #pragma unroll
        for (int in = 0; in < 4; in++)
          acc[im][in] = __builtin_amdgcn_mfma_f32_16x16x32_bf16(
              af[im], bfr[in], acc[im][in], 0, 0, 0);
    }
    __syncthreads();
  }

  #pragma unroll
  for (int im = 0; im < 4; im++) {
    #pragma unroll
    for (int r = 0; r < 4; r++) {
      float rowsum = 0.f;
      #pragma unroll
      for (int in = 0; in < 4; in++) {
        int a_g = ntile * 128 + wn * 64 + in * 16 + l15;
        float v = acc[im][in][r] + pb[a_g];
        rowsum += fast_tanh(v) * ctx[a_g];
      }
      #pragma unroll
      for (int m = 1; m < 16; m <<= 1)
        rowsum += __shfl_xor(rowsum, m, 64);
      if (l15 == 0) {
        int rowg = mtile * 128 + wm * 64 + im * 16 + g * 4 + r;
        sp[(size_t)(ntile * 2 + wn) * MROWS + rowg] = rowsum;
      }
    }
  }
}

// ---------- pass 2: masked softmax ----------
__global__ __launch_bounds__(256) void softmax_kernel(
    const float* __restrict__ sp, const void* __restrict__ lens,
    float* __restrict__ wts)
{
  int b = blockIdx.x;
  int tid = threadIdx.x;
  int len = read_len(lens, b);
  float sc[8];
  #pragma unroll
  for (int i = 0; i < 8; i++) {
    int s = tid + i * 256;
    size_t row = (size_t)b * SS + s;
    float v = 0.f;
    #pragma unroll
    for (int p = 0; p < 8; p++) v += sp[(size_t)p * MROWS + row];
    sc[i] = v;
  }
  float m = -1e30f;
  #pragma unroll
  for (int i = 0; i < 8; i++)
    if (tid + i * 256 < len) m = fmaxf(m, sc[i]);
  #pragma unroll
  for (int off = 1; off < 64; off <<= 1) m = fmaxf(m, __shfl_xor(m, off, 64));
  __shared__ float redm[4];
  __shared__ float reds[4];
  int w = tid >> 6, lane = tid & 63;
  if (lane == 0) redm[w] = m;
  __syncthreads();
  m = fmaxf(fmaxf(redm[0], redm[1]), fmaxf(redm[2], redm[3]));
  float e[8]; float sum = 0.f;
  #pragma unroll
  for (int i = 0; i < 8; i++) {
    int s = tid + i * 256;
    e[i] = (s < len) ? __expf(sc[i] - m) : 0.f;
    sum += e[i];
  }
  #pragma unroll
  for (int off = 1; off < 64; off <<= 1) sum += __shfl_xor(sum, off, 64);
  if (lane == 0) reds[w] = sum;
  __syncthreads();
  sum = reds[0] + reds[1] + reds[2] + reds[3];
  float inv = 1.f / sum;
  #pragma unroll
  for (int i = 0; i < 8; i++) {
    int s = tid + i * 256;
    wts[(size_t)b * SS + s] = e[i] * inv;
  }
}

// ---------- pass 3: weighted sum over s ----------
__global__ __launch_bounds__(256) void wsum_kernel(
    const float* __restrict__ X, const float* __restrict__ wts,
    float* __restrict__ op)
{
  int sc = blockIdx.x;
  int b  = blockIdx.y;
  int tid = threadIdx.x;
  float a0 = 0.f, a1 = 0.f;
  int s0 = sc * 128;
  for (int i = 0; i < 128; i++) {
    int s = s0 + i;
    float wv = wts[(size_t)b * SS + s];
    if (wv != 0.f) {
      const float* xr = X + ((size_t)b * SS + s) * HH;
      a0 += wv * xr[tid];
      a1 += wv * xr[tid + 256];
    }
  }
  float* o = op + ((size_t)sc * BB + b) * HH;
  o[tid] = a0;
  o[tid + 256] = a1;
}

__global__ __launch_bounds__(512) void reduce_kernel(
    const float* __restrict__ op, float* __restrict__ out)
{
  int b = blockIdx.x;
  int h = threadIdx.x;
  float v = 0.f;
  #pragma unroll
  for (int sc = 0; sc < 16; sc++) v += op[((size_t)sc * BB + b) * HH + h];
  out[(size_t)b * SS * 0 + (size_t)b * HH + h] = v;
}

extern "C" void kernel_launch(void* const* d_in, const int* in_sizes, int n_in,
                              void* d_out, int out_size, void* d_ws, size_t ws_size,
                              hipStream_t stream) {
  const float* X   = (const float*)d_in[0];
  const void*  lens = d_in[1];
  const float* ctx = (const float*)d_in[2];
  const float* W   = (const float*)d_in[3];
  const float* pb  = (const float*)d_in[4];
  float* out = (float*)d_out;

  char* ws = (char*)d_ws;
  const size_t XB_BYTES = (size_t)MROWS * HH * 2;          // 128 MB
  const size_t WB_BYTES = (size_t)HH * HH * 2;             // 512 KB
  const size_t SP_BYTES = 8ull * MROWS * 4;                // 4 MB
  const size_t WT_BYTES = (size_t)BB * SS * 4;             // 512 KB
  const size_t OP_BYTES = 16ull * BB * HH * 4;             // 2 MB
  const size_t NEED = XB_BYTES + WB_BYTES + SP_BYTES + WT_BYTES + OP_BYTES;

  if (ws_size >= NEED) {
    unsigned short* Xb = (unsigned short*)ws;
    unsigned short* Wb = (unsigned short*)(ws + XB_BYTES);
    float* sp  = (float*)(ws + XB_BYTES + WB_BYTES);
    float* wts = (float*)(ws + XB_BYTES + WB_BYTES + SP_BYTES);
    float* op  = (float*)(ws + XB_BYTES + WB_BYTES + SP_BYTES + WT_BYTES);

    convw_kernel<<<256, 256, 0, stream>>>(W, Wb);
    convx_kernel<<<2048, 256, 0, stream>>>(X, lens, Xb);
    scores_mfma<<<4096, 256, 0, stream>>>(Xb, Wb, lens, ctx, pb, sp);
    softmax_kernel<<<BB, 256, 0, stream>>>(sp, lens, wts);
    wsum_kernel<<<dim3(16, BB), 256, 0, stream>>>(X, wts, op);
    reduce_kernel<<<BB, 512, 0, stream>>>(op, out);
  } else {
    float* sp  = (float*)ws;
    float* wts = (float*)(ws + SP_BYTES);
    float* op  = (float*)(ws + SP_BYTES + WT_BYTES);

    scores_fb<<<4096, 256, 0, stream>>>(X, lens, ctx, W, pb, sp);
    softmax_kernel<<<BB, 256, 0, stream>>>(sp, lens, wts);
    wsum_kernel<<<dim3(16, BB), 256, 0, stream>>>(X, wts, op);
    reduce_kernel<<<BB, 512, 0, stream>>>(op, out);
  }
}

// Round 3
// 162.416 us; speedup vs baseline: 1.1077x; 1.1048x over previous
//
#include <hip/hip_runtime.h>

#define BB 64
#define SS 2048
#define HH 512
#define MROWS (BB*SS)  // 131072

typedef __attribute__((ext_vector_type(8))) short short8;
typedef __attribute__((ext_vector_type(4))) float f32x4;

__device__ inline unsigned short f2bf(float f){
  unsigned int u = __float_as_uint(f);
  u += 0x7FFFu + ((u >> 16) & 1u);   // RNE
  return (unsigned short)(u >> 16);
}
__device__ inline float bf2f(unsigned short u){
  return __uint_as_float((unsigned int)u << 16);
}

// batch_lens may be int64 (reference) or int32. For int64 LE the high word of
// element 0 is 0 (lens in [1,2048]); for int32, p[1] is a len >= 1.
__device__ inline int read_len(const void* lens, int i){
  const int* p = (const int*)lens;
  if (p[1] == 0) return (int)((const long long*)lens)[i];
  return p[i];
}

__device__ inline float fast_tanh(float x){
  x = fminf(fmaxf(x, -15.f), 15.f);
  float e = __expf(2.f * x);
  return (e - 1.f) / (e + 1.f);
}

__device__ inline void gload16(const void* gptr, void* lptr){
  __builtin_amdgcn_global_load_lds(
      (const __attribute__((address_space(1))) void*)gptr,
      (__attribute__((address_space(3))) void*)lptr, 16, 0, 0);
}

// ---------- pre-convert X and W to bf16 (one kernel) ----------
__global__ __launch_bounds__(256) void convxw_kernel(
    const float* __restrict__ X, const void* __restrict__ lens,
    const float* __restrict__ W,
    unsigned short* __restrict__ Xb, unsigned short* __restrict__ Wb)
{
  int bid = blockIdx.x;
  const float* src;
  unsigned short* dst;
  size_t base;
  if (bid < 2048) {
    int r0 = bid * 64;
    if ((r0 & (SS - 1)) >= read_len(lens, r0 >> 11)) return;  // fully masked
    src = X; dst = Xb; base = (size_t)r0 * HH;
  } else {
    src = W; dst = Wb; base = (size_t)(bid - 2048) * 64 * HH;  // 8 blocks
  }
  int t = threadIdx.x;
  #pragma unroll
  for (int j = 0; j < 32; j++) {
    size_t idx = base + (size_t)j * 1024 + t * 4;
    float4 v = *(const float4*)(src + idx);
    unsigned int p0 = (unsigned int)f2bf(v.x) | ((unsigned int)f2bf(v.y) << 16);
    unsigned int p1 = (unsigned int)f2bf(v.z) | ((unsigned int)f2bf(v.w) << 16);
    *(uint2*)(dst + idx) = make_uint2(p0, p1);
  }
}

// ---------- pass 1: scores via bf16 MFMA, gload_lds staging, swizzled LDS ----------
__global__ __launch_bounds__(256) void scores_mfma(
    const unsigned short* __restrict__ Xb, const unsigned short* __restrict__ Wb,
    const void* __restrict__ lens, const float* __restrict__ ctx,
    const float* __restrict__ pb, float* __restrict__ sp)
{
  int bid = blockIdx.x;
  int wg = (bid & 7) * 512 + (bid >> 3);   // XCD-chunk swizzle (4096 % 8 == 0)
  int ntile = wg & 3;
  int mtile = wg >> 2;
  int s_start = (mtile * 128) & (SS - 1);
  int b = (mtile * 128) >> 11;
  if (s_start >= read_len(lens, b)) return;

  __shared__ __align__(16) unsigned short As[128 * 64];
  __shared__ __align__(16) unsigned short Bs[128 * 64];

  int tid = threadIdx.x;
  int lane = tid & 63;
  int w = tid >> 6;
  int wm = w >> 1, wn = w & 1;
  int l15 = lane & 15, g = lane >> 4;

  f32x4 acc[4][4];
  #pragma unroll
  for (int i = 0; i < 4; i++)
    #pragma unroll
    for (int j = 0; j < 4; j++) acc[i][j] = (f32x4)0.f;

  // staging: wave w, instr i covers LDS rows rb = i*32 + w*8 .. +8 (rb%8==0).
  // lane l -> LDS slot (row rb + (l>>3), phys group l&7); inverse-swizzled
  // global source group (l&7) ^ (l>>3).
  int lrow = lane >> 3;
  int lgrp = (lane & 7) ^ lrow;
  const unsigned short* Arow = Xb + ((size_t)(mtile * 128) + w * 8 + lrow) * HH + lgrp * 8;
  const unsigned short* Brow = Wb + ((size_t)(ntile * 128) + w * 8 + lrow) * HH + lgrp * 8;

  for (int kt = 0; kt < HH; kt += 64) {
    #pragma unroll
    for (int i = 0; i < 4; i++) {
      gload16(Arow + (size_t)(i * 32) * HH + kt, &As[(i * 32 + w * 8) * 64]);
      gload16(Brow + (size_t)(i * 32) * HH + kt, &Bs[(i * 32 + w * 8) * 64]);
    }
    __syncthreads();
    #pragma unroll
    for (int kk = 0; kk < 64; kk += 32) {
      short8 af[4], bfr[4];
      int lgbase = g + (kk >> 3);          // logical 16B-group 0..3 / 4..7
      #pragma unroll
      for (int im = 0; im < 4; im++) {
        int r = wm * 64 + im * 16 + l15;
        int pg = lgbase ^ (r & 7);
        af[im] = *(const short8*)&As[r * 64 + pg * 8];
      }
      #pragma unroll
      for (int in = 0; in < 4; in++) {
        int r = wn * 64 + in * 16 + l15;
        int pg = lgbase ^ (r & 7);
        bfr[in] = *(const short8*)&Bs[r * 64 + pg * 8];
      }
      #pragma unroll
      for (int im = 0; im < 4; im++)
        #pragma unroll
        for (int in = 0; in < 4; in++)
          acc[im][in] = __builtin_amdgcn_mfma_f32_16x16x32_bf16(
              af[im], bfr[in], acc[im][in], 0, 0, 0);
    }
    __syncthreads();
  }

  // Epilogue: tanh(P + pb)*ctx, reduce over the tile's 128 A-cols.
  float pbv[4], ctxv[4];
  #pragma unroll
  for (int in = 0; in < 4; in++) {
    int a_g = ntile * 128 + wn * 64 + in * 16 + l15;
    pbv[in] = pb[a_g];
    ctxv[in] = ctx[a_g];
  }
  #pragma unroll
  for (int im = 0; im < 4; im++) {
    #pragma unroll
    for (int r = 0; r < 4; r++) {
      float rowsum = 0.f;
      #pragma unroll
      for (int in = 0; in < 4; in++)
        rowsum += fast_tanh(acc[im][in][r] + pbv[in]) * ctxv[in];
      #pragma unroll
      for (int m = 1; m < 16; m <<= 1)
        rowsum += __shfl_xor(rowsum, m, 64);
      if (l15 == 0) {
        int rowg = mtile * 128 + wm * 64 + im * 16 + g * 4 + r;
        sp[(size_t)(ntile * 2 + wn) * MROWS + rowg] = rowsum;
      }
    }
  }
}

// ---------- pass 2: masked softmax ----------
__global__ __launch_bounds__(256) void softmax_kernel(
    const float* __restrict__ sp, const void* __restrict__ lens,
    float* __restrict__ wts)
{
  int b = blockIdx.x;
  int tid = threadIdx.x;
  int len = read_len(lens, b);
  float sc[8];
  #pragma unroll
  for (int i = 0; i < 8; i++) {
    int s = tid + i * 256;
    size_t row = (size_t)b * SS + s;
    float v = 0.f;
    #pragma unroll
    for (int p = 0; p < 8; p++) v += sp[(size_t)p * MROWS + row];
    sc[i] = v;
  }
  float m = -1e30f;
  #pragma unroll
  for (int i = 0; i < 8; i++)
    if (tid + i * 256 < len) m = fmaxf(m, sc[i]);
  #pragma unroll
  for (int off = 1; off < 64; off <<= 1) m = fmaxf(m, __shfl_xor(m, off, 64));
  __shared__ float redm[4];
  __shared__ float reds[4];
  int w = tid >> 6, lane = tid & 63;
  if (lane == 0) redm[w] = m;
  __syncthreads();
  m = fmaxf(fmaxf(redm[0], redm[1]), fmaxf(redm[2], redm[3]));
  float e[8]; float sum = 0.f;
  #pragma unroll
  for (int i = 0; i < 8; i++) {
    int s = tid + i * 256;
    e[i] = (s < len) ? __expf(sc[i] - m) : 0.f;
    sum += e[i];
  }
  #pragma unroll
  for (int off = 1; off < 64; off <<= 1) sum += __shfl_xor(sum, off, 64);
  if (lane == 0) reds[w] = sum;
  __syncthreads();
  sum = reds[0] + reds[1] + reds[2] + reds[3];
  float inv = 1.f / sum;
  #pragma unroll
  for (int i = 0; i < 8; i++) {
    int s = tid + i * 256;
    wts[(size_t)b * SS + s] = e[i] * inv;
  }
}

// ---------- pass 3: weighted sum over s, reading bf16 Xb ----------
__global__ __launch_bounds__(256) void wsum_kernel(
    const unsigned short* __restrict__ Xb, const float* __restrict__ wts,
    const void* __restrict__ lens, float* __restrict__ op)
{
  int sc = blockIdx.x;   // 0..15
  int b  = blockIdx.y;   // 0..63
  int tid = threadIdx.x;
  int s0 = sc * 128;
  int len = read_len(lens, b);
  int cnt = min(128, len - s0);
  float* o = op + ((size_t)sc * BB + b) * HH;
  if (cnt <= 0) {   // fully masked chunk: op is poisoned, must write zeros
    *(float2*)(o + tid * 2) = make_float2(0.f, 0.f);
    return;
  }
  __shared__ float wsh[128];
  __shared__ f32x4 red[128];
  if (tid < 128) wsh[tid] = wts[(size_t)b * SS + s0 + tid];
  __syncthreads();
  int h = (tid & 127) * 4;
  int sr = tid >> 7;
  f32x4 acc = (f32x4)0.f;
  for (int i = sr; i < cnt; i += 2) {
    float wv = wsh[i];
    const unsigned short* xr = Xb + ((size_t)b * SS + s0 + i) * HH + h;
    ushort4 xv = *(const ushort4*)xr;     // 8B coalesced
    acc[0] += wv * bf2f(xv.x);
    acc[1] += wv * bf2f(xv.y);
    acc[2] += wv * bf2f(xv.z);
    acc[3] += wv * bf2f(xv.w);
  }
  if (sr == 1) red[tid & 127] = acc;
  __syncthreads();
  if (sr == 0) {
    f32x4 r2 = red[tid];
    acc[0] += r2[0]; acc[1] += r2[1]; acc[2] += r2[2]; acc[3] += r2[3];
    *(f32x4*)(o + h) = acc;
  }
}

// fallback wsum on fp32 X (only if ws too small for Xb)
__global__ __launch_bounds__(256) void wsum_fb(
    const float* __restrict__ X, const float* __restrict__ wts,
    float* __restrict__ op)
{
  int sc = blockIdx.x;
  int b  = blockIdx.y;
  int tid = threadIdx.x;
  float a0 = 0.f, a1 = 0.f;
  int s0 = sc * 128;
  for (int i = 0; i < 128; i++) {
    int s = s0 + i;
    float wv = wts[(size_t)b * SS + s];
    if (wv != 0.f) {
      const float* xr = X + ((size_t)b * SS + s) * HH;
      a0 += wv * xr[tid];
      a1 += wv * xr[tid + 256];
    }
  }
  float* o = op + ((size_t)sc * BB + b) * HH;
  o[tid] = a0;
  o[tid + 256] = a1;
}

__global__ __launch_bounds__(512) void reduce_kernel(
    const float* __restrict__ op, float* __restrict__ out)
{
  int b = blockIdx.x;
  int h = threadIdx.x;
  float v = 0.f;
  #pragma unroll
  for (int sc = 0; sc < 16; sc++) v += op[((size_t)sc * BB + b) * HH + h];
  out[(size_t)b * HH + h] = v;
}

// ---------- fallback pass 1 (round-1 path, used only if ws too small) ----------
__global__ __launch_bounds__(256) void scores_fb(
    const float* __restrict__ X, const void* __restrict__ lens,
    const float* __restrict__ ctx, const float* __restrict__ W,
    const float* __restrict__ pb, float* __restrict__ sp)
{
  int bid = blockIdx.x;
  int wg = (bid & 7) * 512 + (bid >> 3);
  int ntile = wg & 3;
  int mtile = wg >> 2;
  int s_start = (mtile * 128) & (SS - 1);
  int b = (mtile * 128) >> 11;
  if (s_start >= read_len(lens, b)) return;

  __shared__ unsigned short As[128 * 72];
  __shared__ unsigned short Bs[128 * 72];

  int tid = threadIdx.x;
  int lane = tid & 63;
  int w = tid >> 6;
  int wm = w >> 1, wn = w & 1;
  int l15 = lane & 15, g = lane >> 4;

  f32x4 acc[4][4];
  #pragma unroll
  for (int i = 0; i < 4; i++)
    #pragma unroll
    for (int j = 0; j < 4; j++) acc[i][j] = (f32x4)0.f;

  int srow = tid >> 4;
  int scol = (tid & 15) * 4;
  const float* Xbase = X + (size_t)(mtile * 128) * HH;
  const float* Wbase = W + (size_t)(ntile * 128) * HH;

  for (int kt = 0; kt < HH; kt += 64) {
    #pragma unroll
    for (int i = 0; i < 8; i++) {
      int row = srow + i * 16;
      float4 va = *(const float4*)(Xbase + (size_t)row * HH + kt + scol);
      unsigned int p0 = (unsigned int)f2bf(va.x) | ((unsigned int)f2bf(va.y) << 16);
      unsigned int p1 = (unsigned int)f2bf(va.z) | ((unsigned int)f2bf(va.w) << 16);
      *(uint2*)&As[row * 72 + scol] = make_uint2(p0, p1);
      float4 vb = *(const float4*)(Wbase + (size_t)row * HH + kt + scol);
      unsigned int q0 = (unsigned int)f2bf(vb.x) | ((unsigned int)f2bf(vb.y) << 16);
      unsigned int q1 = (unsigned int)f2bf(vb.z) | ((unsigned int)f2bf(vb.w) << 16);
      *(uint2*)&Bs[row * 72 + scol] = make_uint2(q0, q1);
    }
    __syncthreads();
    #pragma unroll
    for (int kk = 0; kk < 64; kk += 32) {
      short8 af[4], bfr[4];
      int ko = kk + g * 8;
      #pragma unroll
      for (int im = 0; im < 4; im++)
        af[im] = *(const short8*)&As[(wm * 64 + im * 16 + l15) * 72 + ko];
      #pragma unroll
      for (int in = 0; in < 4; in++)
        bfr[in] = *(const short8*)&Bs[(wn * 64 + in * 16 + l15) * 72 + ko];
      #pragma unroll
      for (int im = 0; im < 4; im++)
        #pragma unroll
        for (int in = 0; in < 4; in++)
          acc[im][in] = __builtin_amdgcn_mfma_f32_16x16x32_bf16(
              af[im], bfr[in], acc[im][in], 0, 0, 0);
    }
    __syncthreads();
  }

  #pragma unroll
  for (int im = 0; im < 4; im++) {
    #pragma unroll
    for (int r = 0; r < 4; r++) {
      float rowsum = 0.f;
      #pragma unroll
      for (int in = 0; in < 4; in++) {
        int a_g = ntile * 128 + wn * 64 + in * 16 + l15;
        rowsum += fast_tanh(acc[im][in][r] + pb[a_g]) * ctx[a_g];
      }
      #pragma unroll
      for (int m = 1; m < 16; m <<= 1)
        rowsum += __shfl_xor(rowsum, m, 64);
      if (l15 == 0) {
        int rowg = mtile * 128 + wm * 64 + im * 16 + g * 4 + r;
        sp[(size_t)(ntile * 2 + wn) * MROWS + rowg] = rowsum;
      }
    }
  }
}

extern "C" void kernel_launch(void* const* d_in, const int* in_sizes, int n_in,
                              void* d_out, int out_size, void* d_ws, size_t ws_size,
                              hipStream_t stream) {
  const float* X   = (const float*)d_in[0];
  const void*  lens = d_in[1];
  const float* ctx = (const float*)d_in[2];
  const float* W   = (const float*)d_in[3];
  const float* pb  = (const float*)d_in[4];
  float* out = (float*)d_out;

  char* ws = (char*)d_ws;
  const size_t XB_BYTES = (size_t)MROWS * HH * 2;          // 128 MB
  const size_t WB_BYTES = (size_t)HH * HH * 2;             // 512 KB
  const size_t SP_BYTES = 8ull * MROWS * 4;                // 4 MB
  const size_t WT_BYTES = (size_t)BB * SS * 4;             // 512 KB
  const size_t OP_BYTES = 16ull * BB * HH * 4;             // 2 MB
  const size_t NEED = XB_BYTES + WB_BYTES + SP_BYTES + WT_BYTES + OP_BYTES;

  if (ws_size >= NEED) {
    unsigned short* Xb = (unsigned short*)ws;
    unsigned short* Wb = (unsigned short*)(ws + XB_BYTES);
    float* sp  = (float*)(ws + XB_BYTES + WB_BYTES);
    float* wts = (float*)(ws + XB_BYTES + WB_BYTES + SP_BYTES);
    float* op  = (float*)(ws + XB_BYTES + WB_BYTES + SP_BYTES + WT_BYTES);

    convxw_kernel<<<2056, 256, 0, stream>>>(X, lens, W, Xb, Wb);
    scores_mfma<<<4096, 256, 0, stream>>>(Xb, Wb, lens, ctx, pb, sp);
    softmax_kernel<<<BB, 256, 0, stream>>>(sp, lens, wts);
    wsum_kernel<<<dim3(16, BB), 256, 0, stream>>>(Xb, wts, lens, op);
    reduce_kernel<<<BB, 512, 0, stream>>>(op, out);
  } else {
    float* sp  = (float*)ws;
    float* wts = (float*)(ws + SP_BYTES);
    float* op  = (float*)(ws + SP_BYTES + WT_BYTES);

    scores_fb<<<4096, 256, 0, stream>>>(X, lens, ctx, W, pb, sp);
    softmax_kernel<<<BB, 256, 0, stream>>>(sp, lens, wts);
    wsum_fb<<<dim3(16, BB), 256, 0, stream>>>(X, wts, op);
    reduce_kernel<<<BB, 512, 0, stream>>>(op, out);
  }
}

// Round 4
// 143.397 us; speedup vs baseline: 1.2546x; 1.1326x over previous
//
#include <hip/hip_runtime.h>

#define BB 64
#define SS 2048
#define HH 512
#define MROWS (BB*SS)  // 131072

typedef __attribute__((ext_vector_type(8))) short short8;
typedef __attribute__((ext_vector_type(4))) float f32x4;

__device__ inline unsigned short f2bf(float f){
  unsigned int u = __float_as_uint(f);
  u += 0x7FFFu + ((u >> 16) & 1u);   // RNE
  return (unsigned short)(u >> 16);
}
__device__ inline float bf2f(unsigned short u){
  return __uint_as_float((unsigned int)u << 16);
}

// batch_lens may be int64 (reference) or int32. For int64 LE the high word of
// element 0 is 0 (lens in [1,2048]); for int32, p[1] is a len >= 1.
__device__ inline int read_len(const void* lens, int i){
  const int* p = (const int*)lens;
  if (p[1] == 0) return (int)((const long long*)lens)[i];
  return p[i];
}

__device__ inline float fast_tanh(float x){
  x = fminf(fmaxf(x, -15.f), 15.f);
  float e = __expf(2.f * x);
  return (e - 1.f) / (e + 1.f);
}

__device__ inline void gload16(const void* gptr, void* lptr){
  __builtin_amdgcn_global_load_lds(
      (const __attribute__((address_space(1))) void*)gptr,
      (__attribute__((address_space(3))) void*)lptr, 16, 0, 0);
}

__device__ inline short8 cvt8(f32x4 x0, f32x4 x1){
  short8 r;
  r[0] = (short)f2bf(x0[0]); r[1] = (short)f2bf(x0[1]);
  r[2] = (short)f2bf(x0[2]); r[3] = (short)f2bf(x0[3]);
  r[4] = (short)f2bf(x1[0]); r[5] = (short)f2bf(x1[1]);
  r[6] = (short)f2bf(x1[2]); r[7] = (short)f2bf(x1[3]);
  return r;
}

// ---------- tiny pre-convert: W only (1 MB -> 512 KB bf16) ----------
__global__ __launch_bounds__(256) void convw_kernel(
    const float* __restrict__ W, unsigned short* __restrict__ Wb)
{
  size_t base = (size_t)blockIdx.x * 64 * HH;
  int t = threadIdx.x;
  #pragma unroll
  for (int j = 0; j < 32; j++) {
    size_t idx = base + (size_t)j * 1024 + t * 4;
    float4 v = *(const float4*)(W + idx);
    unsigned int p0 = (unsigned int)f2bf(v.x) | ((unsigned int)f2bf(v.y) << 16);
    unsigned int p1 = (unsigned int)f2bf(v.z) | ((unsigned int)f2bf(v.w) << 16);
    *(uint2*)(Wb + idx) = make_uint2(p0, p1);
  }
}

// ---------- pass 1: scores. A staged fp32 via gload_lds, cvt at frag read ----------
__global__ __launch_bounds__(256) void scores_mfma(
    const float* __restrict__ X, const unsigned short* __restrict__ Wb,
    const void* __restrict__ lens, const float* __restrict__ ctx,
    const float* __restrict__ pb, float* __restrict__ sp)
{
  int bid = blockIdx.x;
  int wg = (bid & 7) * 512 + (bid >> 3);   // XCD-chunk swizzle (4096 % 8 == 0)
  int ntile = wg & 3;
  int mtile = wg >> 2;
  int s_start = (mtile * 128) & (SS - 1);
  int b = (mtile * 128) >> 11;
  if (s_start >= read_len(lens, b)) return;

  __shared__ __align__(16) float          Asf[128 * 64];     // 32 KB fp32
  __shared__ __align__(16) unsigned short Bs[128 * 64];      // 16 KB bf16

  int tid = threadIdx.x;
  int lane = tid & 63;
  int w = tid >> 6;
  int wm = w >> 1, wn = w & 1;
  int l15 = lane & 15, g = lane >> 4;

  f32x4 acc[4][4];
  #pragma unroll
  for (int i = 0; i < 4; i++)
    #pragma unroll
    for (int j = 0; j < 4; j++) acc[i][j] = (f32x4)0.f;

  // ---- A staging geometry (fp32, 16-group XOR swizzle) ----
  // wave w, instr i: LDS rows r0 = w*32 + i*4 (+ lane>>4), phys 16B-group lane&15.
  // Inverse swizzle on the global source: logical group = (lane&15) ^ (row & 15).
  int arow_off = lane >> 4;              // 0..3
  int ap = lane & 15;                    // phys group
  // ---- B staging geometry (bf16, 8-group XOR swizzle), as verified ----
  int brow = lane >> 3;                  // 0..7
  int bgrp = (lane & 7) ^ brow;          // inverse-swizzled source group
  const unsigned short* Brow = Wb + ((size_t)(ntile * 128) + w * 8 + brow) * HH + bgrp * 8;

  const float* Abase = X + (size_t)(mtile * 128) * HH;

  for (int kt = 0; kt < HH; kt += 64) {
    // A: 8 gloads/wave, 4 rows each (1 KB per instr)
    #pragma unroll
    for (int i = 0; i < 8; i++) {
      int row = w * 32 + i * 4 + arow_off;
      int g16 = ap ^ (row & 15);
      gload16(Abase + (size_t)row * HH + kt + g16 * 4,
              &Asf[(w * 32 + i * 4) * 64]);
    }
    // B: 4 gloads/wave (bf16)
    #pragma unroll
    for (int i = 0; i < 4; i++) {
      gload16(Brow + (size_t)(i * 32) * HH + kt, &Bs[(i * 32 + w * 8) * 64]);
    }
    __syncthreads();
    #pragma unroll
    for (int kk = 0; kk < 64; kk += 32) {
      short8 af[4], bfr[4];
      int ga0 = (kk >> 2) + 2 * g;       // logical 16B-group (fp32): 0..15
      #pragma unroll
      for (int im = 0; im < 4; im++) {
        int r = wm * 64 + im * 16 + l15;
        f32x4 x0 = *(const f32x4*)&Asf[r * 64 + ((ga0)     ^ l15) * 4];
        f32x4 x1 = *(const f32x4*)&Asf[r * 64 + ((ga0 + 1) ^ l15) * 4];
        af[im] = cvt8(x0, x1);
      }
      int gb = g + (kk >> 3);            // logical 16B-group (bf16): 0..7
      #pragma unroll
      for (int in = 0; in < 4; in++) {
        int r = wn * 64 + in * 16 + l15;
        int pg = gb ^ (r & 7);
        bfr[in] = *(const short8*)&Bs[r * 64 + pg * 8];
      }
      #pragma unroll
      for (int im = 0; im < 4; im++)
        #pragma unroll
        for (int in = 0; in < 4; in++)
          acc[im][in] = __builtin_amdgcn_mfma_f32_16x16x32_bf16(
              af[im], bfr[in], acc[im][in], 0, 0, 0);
    }
    __syncthreads();
  }

  // Epilogue: tanh(P + pb)*ctx, reduce over the tile's 128 A-cols.
  float pbv[4], ctxv[4];
  #pragma unroll
  for (int in = 0; in < 4; in++) {
    int a_g = ntile * 128 + wn * 64 + in * 16 + l15;
    pbv[in] = pb[a_g];
    ctxv[in] = ctx[a_g];
  }
  #pragma unroll
  for (int im = 0; im < 4; im++) {
    #pragma unroll
    for (int r = 0; r < 4; r++) {
      float rowsum = 0.f;
      #pragma unroll
      for (int in = 0; in < 4; in++)
        rowsum += fast_tanh(acc[im][in][r] + pbv[in]) * ctxv[in];
      #pragma unroll
      for (int m = 1; m < 16; m <<= 1)
        rowsum += __shfl_xor(rowsum, m, 64);
      if (l15 == 0) {
        int rowg = mtile * 128 + wm * 64 + im * 16 + g * 4 + r;
        sp[(size_t)(ntile * 2 + wn) * MROWS + rowg] = rowsum;
      }
    }
  }
}

// ---------- pass 2: masked softmax ----------
__global__ __launch_bounds__(256) void softmax_kernel(
    const float* __restrict__ sp, const void* __restrict__ lens,
    float* __restrict__ wts)
{
  int b = blockIdx.x;
  int tid = threadIdx.x;
  int len = read_len(lens, b);
  float sc[8];
  #pragma unroll
  for (int i = 0; i < 8; i++) {
    int s = tid + i * 256;
    size_t row = (size_t)b * SS + s;
    float v = 0.f;
    #pragma unroll
    for (int p = 0; p < 8; p++) v += sp[(size_t)p * MROWS + row];
    sc[i] = v;
  }
  float m = -1e30f;
  #pragma unroll
  for (int i = 0; i < 8; i++)
    if (tid + i * 256 < len) m = fmaxf(m, sc[i]);
  #pragma unroll
  for (int off = 1; off < 64; off <<= 1) m = fmaxf(m, __shfl_xor(m, off, 64));
  __shared__ float redm[4];
  __shared__ float reds[4];
  int w = tid >> 6, lane = tid & 63;
  if (lane == 0) redm[w] = m;
  __syncthreads();
  m = fmaxf(fmaxf(redm[0], redm[1]), fmaxf(redm[2], redm[3]));
  float e[8]; float sum = 0.f;
  #pragma unroll
  for (int i = 0; i < 8; i++) {
    int s = tid + i * 256;
    e[i] = (s < len) ? __expf(sc[i] - m) : 0.f;
    sum += e[i];
  }
  #pragma unroll
  for (int off = 1; off < 64; off <<= 1) sum += __shfl_xor(sum, off, 64);
  if (lane == 0) reds[w] = sum;
  __syncthreads();
  sum = reds[0] + reds[1] + reds[2] + reds[3];
  float inv = 1.f / sum;
  #pragma unroll
  for (int i = 0; i < 8; i++) {
    int s = tid + i * 256;
    wts[(size_t)b * SS + s] = e[i] * inv;
  }
}

// ---------- pass 3: weighted sum over s (fp32 X, L3-warm) ----------
__global__ __launch_bounds__(256) void wsum_kernel(
    const float* __restrict__ X, const float* __restrict__ wts,
    const void* __restrict__ lens, float* __restrict__ op)
{
  int sc = blockIdx.x;   // 0..15
  int b  = blockIdx.y;   // 0..63
  int tid = threadIdx.x;
  int s0 = sc * 128;
  int len = read_len(lens, b);
  int cnt = min(128, len - s0);
  float* o = op + ((size_t)sc * BB + b) * HH;
  if (cnt <= 0) {   // fully masked chunk: op is poisoned, must write zeros
    *(float2*)(o + tid * 2) = make_float2(0.f, 0.f);
    return;
  }
  __shared__ float wsh[128];
  __shared__ f32x4 red[128];
  if (tid < 128) wsh[tid] = wts[(size_t)b * SS + s0 + tid];
  __syncthreads();
  int h = (tid & 127) * 4;
  int sr = tid >> 7;
  f32x4 acc = (f32x4)0.f;
  for (int i = sr; i < cnt; i += 2) {
    float wv = wsh[i];
    const float* xr = X + ((size_t)b * SS + s0 + i) * HH + h;
    float4 xv = *(const float4*)xr;       // 16B coalesced
    acc[0] += wv * xv.x;
    acc[1] += wv * xv.y;
    acc[2] += wv * xv.z;
    acc[3] += wv * xv.w;
  }
  if (sr == 1) red[tid & 127] = acc;
  __syncthreads();
  if (sr == 0) {
    f32x4 r2 = red[tid];
    acc[0] += r2[0]; acc[1] += r2[1]; acc[2] += r2[2]; acc[3] += r2[3];
    *(f32x4*)(o + h) = acc;
  }
}

__global__ __launch_bounds__(512) void reduce_kernel(
    const float* __restrict__ op, float* __restrict__ out)
{
  int b = blockIdx.x;
  int h = threadIdx.x;
  float v = 0.f;
  #pragma unroll
  for (int sc = 0; sc < 16; sc++) v += op[((size_t)sc * BB + b) * HH + h];
  out[(size_t)b * HH + h] = v;
}

// ---------- fallback pass 1 (reg-staged, used only if ws too small) ----------
__global__ __launch_bounds__(256) void scores_fb(
    const float* __restrict__ X, const void* __restrict__ lens,
    const float* __restrict__ ctx, const float* __restrict__ W,
    const float* __restrict__ pb, float* __restrict__ sp)
{
  int bid = blockIdx.x;
  int wg = (bid & 7) * 512 + (bid >> 3);
  int ntile = wg & 3;
  int mtile = wg >> 2;
  int s_start = (mtile * 128) & (SS - 1);
  int b = (mtile * 128) >> 11;
  if (s_start >= read_len(lens, b)) return;

  __shared__ unsigned short As[128 * 72];
  __shared__ unsigned short Bs[128 * 72];

  int tid = threadIdx.x;
  int lane = tid & 63;
  int w = tid >> 6;
  int wm = w >> 1, wn = w & 1;
  int l15 = lane & 15, g = lane >> 4;

  f32x4 acc[4][4];
  #pragma unroll
  for (int i = 0; i < 4; i++)
    #pragma unroll
    for (int j = 0; j < 4; j++) acc[i][j] = (f32x4)0.f;

  int srow = tid >> 4;
  int scol = (tid & 15) * 4;
  const float* Xbase = X + (size_t)(mtile * 128) * HH;
  const float* Wbase = W + (size_t)(ntile * 128) * HH;

  for (int kt = 0; kt < HH; kt += 64) {
    #pragma unroll
    for (int i = 0; i < 8; i++) {
      int row = srow + i * 16;
      float4 va = *(const float4*)(Xbase + (size_t)row * HH + kt + scol);
      unsigned int p0 = (unsigned int)f2bf(va.x) | ((unsigned int)f2bf(va.y) << 16);
      unsigned int p1 = (unsigned int)f2bf(va.z) | ((unsigned int)f2bf(va.w) << 16);
      *(uint2*)&As[row * 72 + scol] = make_uint2(p0, p1);
      float4 vb = *(const float4*)(Wbase + (size_t)row * HH + kt + scol);
      unsigned int q0 = (unsigned int)f2bf(vb.x) | ((unsigned int)f2bf(vb.y) << 16);
      unsigned int q1 = (unsigned int)f2bf(vb.z) | ((unsigned int)f2bf(vb.w) << 16);
      *(uint2*)&Bs[row * 72 + scol] = make_uint2(q0, q1);
    }
    __syncthreads();
    #pragma unroll
    for (int kk = 0; kk < 64; kk += 32) {
      short8 af[4], bfr[4];
      int ko = kk + g * 8;
      #pragma unroll
      for (int im = 0; im < 4; im++)
        af[im] = *(const short8*)&As[(wm * 64 + im * 16 + l15) * 72 + ko];
      #pragma unroll
      for (int in = 0; in < 4; in++)
        bfr[in] = *(const short8*)&Bs[(wn * 64 + in * 16 + l15) * 72 + ko];
      #pragma unroll
      for (int im = 0; im < 4; im++)
        #pragma unroll
        for (int in = 0; in < 4; in++)
          acc[im][in] = __builtin_amdgcn_mfma_f32_16x16x32_bf16(
              af[im], bfr[in], acc[im][in], 0, 0, 0);
    }
    __syncthreads();
  }

  #pragma unroll
  for (int im = 0; im < 4; im++) {
    #pragma unroll
    for (int r = 0; r < 4; r++) {
      float rowsum = 0.f;
      #pragma unroll
      for (int in = 0; in < 4; in++) {
        int a_g = ntile * 128 + wn * 64 + in * 16 + l15;
        rowsum += fast_tanh(acc[im][in][r] + pb[a_g]) * ctx[a_g];
      }
      #pragma unroll
      for (int m = 1; m < 16; m <<= 1)
        rowsum += __shfl_xor(rowsum, m, 64);
      if (l15 == 0) {
        int rowg = mtile * 128 + wm * 64 + im * 16 + g * 4 + r;
        sp[(size_t)(ntile * 2 + wn) * MROWS + rowg] = rowsum;
      }
    }
  }
}

extern "C" void kernel_launch(void* const* d_in, const int* in_sizes, int n_in,
                              void* d_out, int out_size, void* d_ws, size_t ws_size,
                              hipStream_t stream) {
  const float* X   = (const float*)d_in[0];
  const void*  lens = d_in[1];
  const float* ctx = (const float*)d_in[2];
  const float* W   = (const float*)d_in[3];
  const float* pb  = (const float*)d_in[4];
  float* out = (float*)d_out;

  char* ws = (char*)d_ws;
  const size_t WB_BYTES = (size_t)HH * HH * 2;             // 512 KB
  const size_t SP_BYTES = 8ull * MROWS * 4;                // 4 MB
  const size_t WT_BYTES = (size_t)BB * SS * 4;             // 512 KB
  const size_t OP_BYTES = 16ull * BB * HH * 4;             // 2 MB
  const size_t NEED = WB_BYTES + SP_BYTES + WT_BYTES + OP_BYTES;

  if (ws_size >= NEED) {
    unsigned short* Wb = (unsigned short*)ws;
    float* sp  = (float*)(ws + WB_BYTES);
    float* wts = (float*)(ws + WB_BYTES + SP_BYTES);
    float* op  = (float*)(ws + WB_BYTES + SP_BYTES + WT_BYTES);

    convw_kernel<<<8, 256, 0, stream>>>(W, Wb);
    scores_mfma<<<4096, 256, 0, stream>>>(X, Wb, lens, ctx, pb, sp);
    softmax_kernel<<<BB, 256, 0, stream>>>(sp, lens, wts);
    wsum_kernel<<<dim3(16, BB), 256, 0, stream>>>(X, wts, lens, op);
    reduce_kernel<<<BB, 512, 0, stream>>>(op, out);
  } else {
    float* sp  = (float*)ws;
    float* wts = (float*)(ws + SP_BYTES);
    float* op  = (float*)(ws + SP_BYTES + WT_BYTES);

    scores_fb<<<4096, 256, 0, stream>>>(X, lens, ctx, W, pb, sp);
    softmax_kernel<<<BB, 256, 0, stream>>>(sp, lens, wts);
    wsum_kernel<<<dim3(16, BB), 256, 0, stream>>>(X, wts, lens, op);
    reduce_kernel<<<BB, 512, 0, stream>>>(op, out);
  }
}